// Round 1
// 163.900 us; speedup vs baseline: 1.0538x; 1.0538x over previous
//
#include <hip/hip_runtime.h>
#include <hip/hip_fp16.h>

#define CH      64    // IN_CH == OUT_CH == 64
#define BSHIFT  7     // 128 nodes per bucket
#define BNODES  128
#define MAXBUK  400   // NBUK = ceil(50000/128) = 391
#define CAP     4608  // bucket capacity: mean 4096, sigma~64 -> 8-sigma margin
#define SCAP    1344  // quarter-bucket capacity: mean 1024, sigma~32 -> 10-sigma

union H2U { __half2 h; unsigned u; };

// ---------------------------------------------------------------------------
// Launch 1: init — zero the per-bucket cursors, pack W into half2 pairs
// {W1[k][o], W2[k][o]}. One block.
// ---------------------------------------------------------------------------
__global__ __launch_bounds__(256) void init_kernel(
    int* __restrict__ qcur, int NBUK,
    const float* __restrict__ W, unsigned* __restrict__ Whp)
{
    for (int i = threadIdx.x; i < NBUK; i += 256) qcur[i] = 0;
    for (int i = threadIdx.x; i < 64 * CH; i += 256) {
        int k = i >> 6, o = i & 63;
        H2U u;
        u.h = __floats2half2_rn(W[k * CH + o], W[(64 + k) * CH + o]);
        Whp[i] = u.u;
    }
}

// ---------------------------------------------------------------------------
// Launch 2: binprep — heterogeneous blocks (UNCHANGED, R12-validated).
//   blocks [0, EB):      bin tiles -> fixed-cap bucket regions q[b*CAP+local]
//   blocks [EB, EB+XB):  x (fp32) -> xh (fp16), 4 elems/thread.
// Entry: {bucket<<23 | row_local<<16 | col, attr_f32}.
// ---------------------------------------------------------------------------
__global__ __launch_bounds__(512) void binprep_kernel(
    const int* __restrict__ ei, const float* __restrict__ attr,
    int* __restrict__ qcur, uint2* __restrict__ q, int E, int NBUK,
    const float* __restrict__ x, __half* __restrict__ xh, int total, int EB)
{
    __shared__ int   lcnt[MAXBUK];
    __shared__ int   lrank[MAXBUK];
    __shared__ int   loff[MAXBUK];
    __shared__ int   gloc[MAXBUK];    // local (0-based) reserved base per bucket
    __shared__ int   wsum[8];
    __shared__ uint2 stg[4096];       // 32 KB

    int t = threadIdx.x, wv = t >> 6, ln = t & 63;

    if ((int)blockIdx.x >= EB) {      // ---- conversion blocks ----
        int i = ((blockIdx.x - EB) * 512 + t) * 4;
        if (i + 4 <= total) {
            float4 v = *(const float4*)(x + i);
            H2U h0, h1;
            h0.h = __floats2half2_rn(v.x, v.y);
            h1.h = __floats2half2_rn(v.z, v.w);
            *(uint2*)(xh + i) = make_uint2(h0.u, h1.u);
        }
        return;
    }

    // ---- bin tile ----
    int tbase = blockIdx.x * 4096;
    int m = E - tbase; if (m > 4096) m = 4096;

    for (int i = t; i < NBUK; i += 512) { lcnt[i] = 0; lrank[i] = 0; }
    __syncthreads();

    int ebase = tbase + t * 8;
    int ne = m - t * 8; ne = ne < 0 ? 0 : (ne > 8 ? 8 : ne);

    int rows[8], cols[8]; float av[8];
    if (ne == 8) {
        int4 r0 = *(const int4*)(ei + ebase);
        int4 r1 = *(const int4*)(ei + ebase + 4);
        int4 c0 = *(const int4*)(ei + E + ebase);
        int4 c1 = *(const int4*)(ei + E + ebase + 4);
        float4 a0 = *(const float4*)(attr + ebase);
        float4 a1 = *(const float4*)(attr + ebase + 4);
        rows[0]=r0.x; rows[1]=r0.y; rows[2]=r0.z; rows[3]=r0.w;
        rows[4]=r1.x; rows[5]=r1.y; rows[6]=r1.z; rows[7]=r1.w;
        cols[0]=c0.x; cols[1]=c0.y; cols[2]=c0.z; cols[3]=c0.w;
        cols[4]=c1.x; cols[5]=c1.y; cols[6]=c1.z; cols[7]=c1.w;
        av[0]=a0.x; av[1]=a0.y; av[2]=a0.z; av[3]=a0.w;
        av[4]=a1.x; av[5]=a1.y; av[6]=a1.z; av[7]=a1.w;
    } else {
        #pragma unroll
        for (int j = 0; j < 8; ++j) {
            if (j < ne) { rows[j]=ei[ebase+j]; cols[j]=ei[E+ebase+j]; av[j]=attr[ebase+j]; }
            else        { rows[j]=0; cols[j]=0; av[j]=0.f; }
        }
    }

    #pragma unroll
    for (int j = 0; j < 8; ++j)
        if (j < ne) atomicAdd(&lcnt[rows[j] >> BSHIFT], 1);
    __syncthreads();

    // shfl-based exclusive scan of lcnt
    int v = (t < NBUK) ? lcnt[t] : 0;
    int inc = v;
    #pragma unroll
    for (int d = 1; d < 64; d <<= 1) {
        int u = __shfl_up(inc, d);
        if (ln >= d) inc += u;
    }
    if (ln == 63) wsum[wv] = inc;
    __syncthreads();
    if (wv == 0) {
        int s = (ln < 8) ? wsum[ln] : 0;
        int si = s;
        #pragma unroll
        for (int d = 1; d < 8; d <<= 1) {
            int u = __shfl_up(si, d);
            if (ln >= d) si += u;
        }
        if (ln < 8) wsum[ln] = si - s;
    }
    __syncthreads();
    if (t < NBUK) {
        loff[t] = inc - v + wsum[wv];
        if (v > 0) gloc[t] = atomicAdd(&qcur[t], v);   // local base in bucket
    }
    __syncthreads();

    #pragma unroll
    for (int j = 0; j < 8; ++j) {
        if (j < ne) {
            int bk = rows[j] >> BSHIFT;
            int rk = atomicAdd(&lrank[bk], 1);
            unsigned meta = ((unsigned)bk << 23) |
                            ((unsigned)(rows[j] & (BNODES - 1)) << 16) |
                            (unsigned)cols[j];
            stg[loff[bk] + rk] = make_uint2(meta, __float_as_uint(av[j]));
        }
    }
    __syncthreads();

    for (int i = t; i < m; i += 512) {
        uint2 e = stg[i];
        int bk = (int)(e.x >> 23);
        int lp = gloc[bk] + (i - loff[bk]);    // local position in bucket
        if (lp < CAP)                          // overflow guard (8-sigma)
            q[(size_t)bk * CAP + lp] = e;      // coalesced run writes
    }
}

// ---------------------------------------------------------------------------
// Launch 3: fused sort + gather + epilogue.  localsort is GONE.
// 4 sibling blocks per bucket, 32 nodes each (grid ~1564 == old gather grid,
// so gather's proven scheduling/occupancy is preserved).  Each block:
//   stage:  stream the bucket's q region (coalesced), ballot-filter its
//           quarter (~1024 edges) into an LDS stash (1 LDS atomic per wave
//           per iter), 32-counter shfl scan, scatter to packed LDS sorted[].
//   gather: R11's exact 64-lane-per-node inner loop, edge metadata now read
//           from LDS instead of global q2 (removes 6.4 MB global + latency).
// XCD swizzle: grid padded to mult-of-32 (1568 = 8*196, 196%4==0 so bucket
// quads never straddle a chunk); logical = (phys%8)*chunk + phys/8 puts all
// 4 siblings on one XCD -> 3 of 4 bucket reads are same-L2 hits.
// LDS: 16K Whl + 10.5K stash + 5.25K sorted + ~4.5K misc ~= 36.2 KB
// -> 4 blocks/CU, 32 waves/CU (same as before).
// ---------------------------------------------------------------------------
__device__ __forceinline__ void gstep(
    const __half* __restrict__ xh, unsigned v, int l,
    float& a0, float& a1, float& a2, float& a3, float& sa)
{
    int   col = (int)(v >> 16);
    float a   = __half2float(__ushort_as_half((unsigned short)(v & 0xffffu)));
    uint2 u = *(const uint2*)(xh + (((size_t)col) << 6) + (l << 2));
    H2U u0, u1; u0.u = u.x; u1.u = u.y;
    float2 f0 = __half22float2(u0.h);
    float2 f1 = __half22float2(u1.h);
    a0 += a * f0.x; a1 += a * f0.y; a2 += a * f1.x; a3 += a * f1.y;
    sa += a;
}

__global__ __launch_bounds__(512, 8) void gather_out_kernel(
    const float* __restrict__ x,
    const __half* __restrict__ xh,
    const uint2* __restrict__ q,
    const int* __restrict__ qcur,
    const unsigned* __restrict__ Whp,    // [64*64] packed {W1,W2} half2
    const float* __restrict__ bias,
    float* __restrict__ out,
    int N, int NBUK, int chunk)
{
    __shared__ unsigned Whl[64 * CH];   // 16 KB
    __shared__ uint2    us[SCAP];       // 10.5 KB  unsorted quarter stash
    __shared__ unsigned srt[SCAP];      // 5.25 KB  packed {col<<16|attr_h}
    __shared__ int ncnt[32];
    __shared__ int nst[32];
    __shared__ int cur[32];
    __shared__ int ucnt;
    __shared__ float xs[8][CH];         // 2 KB
    __shared__ float gs[8][CH];         // 2 KB

    int t  = threadIdx.x;
    int ln = t & 63;

    // XCD-aware bijective swizzle (phys%8 == XCD heuristic; perf-only)
    int lb = ((int)blockIdx.x & 7) * chunk + ((int)blockIdx.x >> 3);
    int b  = lb >> 2;                   // bucket
    int qt = lb & 3;                    // 32-node quarter within bucket
    if (b >= NBUK) return;              // padded blocks; uniform, pre-barrier

    for (int i = t; i < 64 * CH; i += 512) Whl[i] = Whp[i];
    if (t < 32) ncnt[t] = 0;
    if (t == 0) ucnt = 0;
    __syncthreads();

    int cnt = qcur[b]; if (cnt > CAP) cnt = CAP;   // uniform -> scalar load
    size_t base8 = (size_t)b * CAP;

    // ---- stage: ballot-filter our quarter into us[] ----
    int cntR = (cnt + 511) & ~511;      // all waves iterate uniformly
    for (int i = t; i < cntR; i += 512) {
        bool act = false; uint2 e = make_uint2(0u, 0u);
        if (i < cnt) {
            e = q[base8 + i];                       // coalesced
            act = (int)((e.x >> 21) & 3u) == qt;    // row_local>>5
        }
        unsigned long long bal = __ballot(act);
        int rk = __popcll(bal & ((1ull << ln) - 1ull));
        int wbase = 0;
        if (ln == 0) wbase = atomicAdd(&ucnt, (int)__popcll(bal));
        wbase = __shfl(wbase, 0);
        if (act) {
            int p = wbase + rk;
            if (p < SCAP) {                         // 10-sigma guard
                int r = (int)((e.x >> 16) & 31u);   // node within quarter
                atomicAdd(&ncnt[r], 1);
                us[p] = make_uint2(((unsigned)r << 16) | (e.x & 0xffffu), e.y);
            }
        }
    }
    __syncthreads();

    // ---- scan 32 counters (wave 0) ----
    if (t < 32) {
        int v = ncnt[t];
        int inc = v;
        #pragma unroll
        for (int d = 1; d < 32; d <<= 1) {
            int u = __shfl_up(inc, d);
            if (ln >= d) inc += u;
        }
        nst[t] = inc - v;
        cur[t] = inc - v;
    }
    __syncthreads();

    // ---- scatter to sorted packed LDS ----
    int m = ucnt < SCAP ? ucnt : SCAP;
    for (int i = t; i < m; i += 512) {
        uint2 e = us[i];
        int r = (int)(e.x >> 16);
        int p = atomicAdd(&cur[r], 1);
        unsigned ah = (unsigned)__half_as_ushort(
                          __float2half(__uint_as_float(e.y)));
        srt[p] = ((e.x & 0xffffu) << 16) | ah;
    }
    __syncthreads();

    // ---- gather + epilogue (R11 structure; edges from LDS) ----
    int w = t >> 6;          // wave in block (0..7)
    int g = ln >> 4;         // edge group
    int l = ln & 15;         // channel-quad
    float bs = bias[ln];

    #pragma unroll
    for (int k = 0; k < 4; ++k) {
        int nl = w * 4 + k;                       // local node 0..31
        int n  = b * BNODES + qt * 32 + nl;
        if (n >= N) continue;                     // wave-uniform branch

        int start = nst[nl];
        int deg   = ncnt[nl];
        int end   = start + deg;

        float a0 = 0.f, a1 = 0.f, a2 = 0.f, a3 = 0.f, sa = 0.f;
        int cb = start;
        for (; cb + 16 <= end; cb += 16) {        // 16 gathers in flight
            unsigned v0 = srt[cb + g];
            unsigned v1 = srt[cb + 4 + g];
            unsigned v2 = srt[cb + 8 + g];
            unsigned v3 = srt[cb + 12 + g];
            gstep(xh, v0, l, a0, a1, a2, a3, sa);
            gstep(xh, v1, l, a0, a1, a2, a3, sa);
            gstep(xh, v2, l, a0, a1, a2, a3, sa);
            gstep(xh, v3, l, a0, a1, a2, a3, sa);
        }
        for (; cb < end; cb += 4) {               // tail chunks of 4
            int  idx = cb + g;
            bool act = idx < end;
            unsigned v = srt[act ? idx : (end - 1)];
            if (!act) v &= 0xffff0000u;           // zero attr for padding
            gstep(xh, v, l, a0, a1, a2, a3, sa);
        }

        a0 += __shfl_down(a0, 32); a1 += __shfl_down(a1, 32);
        a2 += __shfl_down(a2, 32); a3 += __shfl_down(a3, 32);
        sa += __shfl_down(sa, 32);
        a0 += __shfl_down(a0, 16); a1 += __shfl_down(a1, 16);
        a2 += __shfl_down(a2, 16); a3 += __shfl_down(a3, 16);
        sa += __shfl_down(sa, 16);

        if (ln < 16)
            *(float4*)&gs[w][l * 4] = make_float4(a0, a1, a2, a3);
        // BITCAST broadcast (R4 lesson: bare readfirstlane(float) truncates)
        sa = __int_as_float(__builtin_amdgcn_readfirstlane(__float_as_int(sa)));
        xs[w][ln] = x[(size_t)n * CH + ln];
        // same-wave LDS RAW: in-order DS pipe + compiler lgkmcnt, no barrier

        float acc1 = 0.f, acc2 = 0.f;
        #pragma unroll
        for (int kk = 0; kk < CH; ++kk) {
            H2U wv2; wv2.u = Whl[kk * CH + ln];   // conflict-free per-lane 4B
            float2 wf = __half22float2(wv2.h);
            acc1 += xs[w][kk] * wf.x;             // uniform kk -> broadcast
            acc2 += gs[w][kk] * wf.y;
        }

        float c = (float)deg;
        if (c < 1.0f) c = 1.0f;
        out[(size_t)n * CH + ln] = (sa * acc1 + acc2) / c + bs;
    }
}

extern "C" void kernel_launch(void* const* d_in, const int* in_sizes, int n_in,
                              void* d_out, int out_size, void* d_ws, size_t ws_size,
                              hipStream_t stream) {
    const float* x    = (const float*)d_in[0];   // [N, 64] f32
    const int*   ei   = (const int*)d_in[1];     // [2, E] int
    const float* attr = (const float*)d_in[2];   // [E] f32
    const float* W    = (const float*)d_in[3];   // [128, 64] f32
    const float* bias = (const float*)d_in[4];   // [64] f32
    float*       out  = (float*)d_out;           // [N, 64] f32

    int N = in_sizes[0] / CH;     // 50000 (col fits 16 bits; NBUK <= MAXBUK)
    int E = in_sizes[2];          // 1,600,000

    int NBUK = (N + BNODES - 1) >> BSHIFT;   // 391

    // Workspace (~21.1 MB <= proven 26.2 MB):
    //   xh[N*64 half] | q[NBUK*CAP uint2] | nstart[N] | ndeg[N] (now unused,
    //   layout kept) | qcur[NBUK] | Whp[64*64 u32]
    __half*   xh     = (__half*)d_ws;
    uint2*    q      = (uint2*)(xh + (size_t)N * CH);
    int*      nstart = (int*)(q + (size_t)NBUK * CAP);
    int*      ndeg   = nstart + N;
    int*      qcur   = ndeg + N;
    unsigned* Whp    = (unsigned*)(qcur + NBUK);
    (void)nstart; (void)ndeg;

    init_kernel<<<1, 256, 0, stream>>>(qcur, NBUK, W, Whp);

    int total = N * CH;
    int EB = (E + 4095) / 4096;          // 391 bin tiles
    int XB = (total + 2047) / 2048;      // 1563 conversion blocks (512 thr x4)
    binprep_kernel<<<EB + XB, 512, 0, stream>>>(
        ei, attr, qcur, q, E, NBUK, x, xh, total, EB);

    // fused sort+gather: 4 blocks per bucket, grid padded to mult of 32 so
    // the XCD swizzle is bijective and bucket-quads never straddle chunks.
    int NQ = NBUK * 4;                   // 1564
    int G  = (NQ + 31) & ~31;            // 1568 = 8 * 196
    int chunk = G >> 3;                  // 196 (mult of 4)
    gather_out_kernel<<<G, 512, 0, stream>>>(
        x, xh, q, qcur, Whp, bias, out, N, NBUK, chunk);
}